// Round 2
// baseline (2093.287 us; speedup 1.0000x reference)
//
#include <hip/hip_runtime.h>
#include <math.h>

#define T_DIM 2048
#define C_DIM 1024
#define U_DIM 256
#define B_DIM 32
// S = 2U+1 = 513 states, thread tid owns states 8*tid .. 8*tid+7 (+ state 512 on tid 63)

__device__ __forceinline__ float neg2() { return -1.4426950e30f; } // -1e30 / ln2
#define INV_LN2 1.4426950408889634f
#define LN2F    0.6931471805599453f

// ---------------- denominator: per-frame logsumexp, masked sum per b -------------
__global__ __launch_bounds__(256) void den_kernel(const float* __restrict__ lp,
                                                  const int* __restrict__ in_len,
                                                  float* __restrict__ den) {
    const int t = blockIdx.x;
    const int b = blockIdx.y;
    if (t >= in_len[b]) return;  // frame masked out -> contributes 0
    const float* row = lp + ((size_t)b * T_DIM + t) * C_DIM;
    const int tid = threadIdx.x;
    float4 v = reinterpret_cast<const float4*>(row)[tid];
    float m = fmaxf(fmaxf(v.x, v.y), fmaxf(v.z, v.w));
    #pragma unroll
    for (int off = 32; off; off >>= 1) m = fmaxf(m, __shfl_xor(m, off));
    __shared__ float sm[4];
    __shared__ float ss[4];
    const int wid = tid >> 6;
    if ((tid & 63) == 0) sm[wid] = m;
    __syncthreads();
    m = fmaxf(fmaxf(sm[0], sm[1]), fmaxf(sm[2], sm[3]));
    float s = expf(v.x - m) + expf(v.y - m) + expf(v.z - m) + expf(v.w - m);
    #pragma unroll
    for (int off = 32; off; off >>= 1) s += __shfl_xor(s, off);
    if ((tid & 63) == 0) ss[wid] = s;
    __syncthreads();
    if (tid == 0) {
        float tot = ss[0] + ss[1] + ss[2] + ss[3];
        atomicAdd(&den[b], m + logf(tot));
    }
}

// ---------------- numerator: CTC forward recursion, 1 wave per batch element -----
__global__ __launch_bounds__(64) void ctc_alpha_kernel(const float* __restrict__ lp,
                                                       const int* __restrict__ targets,
                                                       const int* __restrict__ in_len,
                                                       const int* __restrict__ tg_len,
                                                       float* __restrict__ num_out) {
    const int b = blockIdx.x;
    const int tid = threadIdx.x;          // 0..63
    const int L = in_len[b];
    const int tgb = b * U_DIM;

    // per-state constants (state s = 8*tid+i for i<8; i==8 is state 512, real only on tid 63)
    int col[9];
    int allow2[9];
    #pragma unroll
    for (int i = 0; i < 9; ++i) {
        const int s = (i < 8) ? (8 * tid + i) : 512;
        int lab = 0;
        if (s & 1) lab = targets[tgb + (s >> 1)];
        col[i] = lab;
        int al = 0;
        if ((s & 1) && s >= 3) al = (targets[tgb + (s >> 1)] != targets[tgb + (s >> 1) - 1]) ? 1 : 0;
        allow2[i] = al;
    }

    const float* rowb = lp + (size_t)b * T_DIM * C_DIM;

    // t = 0 init (base-2 domain)
    float a[9];
    #pragma unroll
    for (int i = 0; i < 9; ++i) {
        const int s = (i < 8) ? (8 * tid + i) : 512;
        const float e = rowb[col[i]] * INV_LN2;
        a[i] = (s <= 1) ? e : neg2();
    }

    // emissions for t=1 (raw, scaled in the loop)
    float eb[9];
    {
        const float* row1 = rowb + C_DIM;
        #pragma unroll
        for (int i = 0; i < 9; ++i) eb[i] = row1[col[i]];
    }

    for (int t = 1; t < L; ++t) {
        // prefetch emissions for t+1 (dummy re-read of row t on the last iter)
        float en[9];
        {
            const int tn = (t + 1 < L) ? (t + 1) : t;
            const float* rown = rowb + (size_t)tn * C_DIM;
            #pragma unroll
            for (int i = 0; i < 9; ++i) en[i] = rown[col[i]];
        }

        float pl  = __shfl_up(a[7], 1);   // old alpha of state 8*tid-1
        float pll = __shfl_up(a[6], 1);   // old alpha of state 8*tid-2
        if (tid == 0) { pl = neg2(); pll = neg2(); }

        float nw[9];
        #pragma unroll
        for (int i = 0; i < 9; ++i) {
            const float self = a[i];
            const float f1 = (i == 0) ? pl : a[i - 1];
            float f2 = (i == 0) ? pll : ((i == 1) ? pl : a[i - 2]);
            f2 = allow2[i] ? f2 : neg2();
            const float m = fmaxf(fmaxf(self, f1), f2);
            const float sum = exp2f(self - m) + exp2f(f1 - m) + exp2f(f2 - m);
            nw[i] = m + log2f(sum) + eb[i] * INV_LN2;
        }
        #pragma unroll
        for (int i = 0; i < 9; ++i) { a[i] = nw[i]; eb[i] = en[i]; }
    }

    // gather final alpha, combine states 2*tl and 2*tl-1
    __shared__ float sA[513];
    #pragma unroll
    for (int i = 0; i < 8; ++i) sA[8 * tid + i] = a[i];
    if (tid == 63) sA[512] = a[8];
    __syncthreads();
    if (tid == 0) {
        const int sl = 2 * tg_len[b];
        const float x = sA[sl], y = sA[sl - 1];
        const float m = fmaxf(x, y);
        const float num2 = m + log2f(exp2f(x - m) + exp2f(y - m));
        num_out[b] = num2 * LN2F;
    }
}

// ---------------- finalize: tot = num - den, validity, mean, outputs -------------
__global__ __launch_bounds__(64) void fin_kernel(const float* __restrict__ num,
                                                 const float* __restrict__ den,
                                                 float* __restrict__ out) {
    const int tid = threadIdx.x;
    float contrib = 0.f, cnt = 0.f;
    if (tid < B_DIM) {
        const float tot = num[tid] - den[tid];
        const bool finite = (tot == tot) && (fabsf(tot) < 3.0e38f);
        const bool valid = finite && (tot > -5.0e29f);
        out[1 + tid] = valid ? 1.0f : 0.0f;
        if (valid) { contrib = tot; cnt = 1.f; }
    }
    #pragma unroll
    for (int off = 32; off; off >>= 1) {
        contrib += __shfl_xor(contrib, off);
        cnt     += __shfl_xor(cnt, off);
    }
    if (tid == 0) {
        out[0] = -(contrib / fmaxf(cnt, 1.f));
    }
}

extern "C" void kernel_launch(void* const* d_in, const int* in_sizes, int n_in,
                              void* d_out, int out_size, void* d_ws, size_t ws_size,
                              hipStream_t stream) {
    const float* lp      = (const float*)d_in[0];
    const int* targets   = (const int*)d_in[1];
    const int* in_len    = (const int*)d_in[2];
    const int* tg_len    = (const int*)d_in[3];
    float* out = (float*)d_out;

    float* den = (float*)d_ws;
    float* num = den + B_DIM;

    hipMemsetAsync(d_ws, 0, 2 * B_DIM * sizeof(float), stream);

    dim3 gden(T_DIM, B_DIM);
    den_kernel<<<gden, 256, 0, stream>>>(lp, in_len, den);
    ctc_alpha_kernel<<<B_DIM, 64, 0, stream>>>(lp, targets, in_len, tg_len, num);
    fin_kernel<<<1, 64, 0, stream>>>(num, den, out);
}